// Round 6
// baseline (412.641 us; speedup 1.0000x reference)
//
#include <hip/hip_runtime.h>

typedef unsigned short u16;
typedef __attribute__((ext_vector_type(8))) short short8;
typedef __attribute__((ext_vector_type(4))) float f32x4;

struct __align__(8) us4 { u16 x, y, z, w; };
struct __align__(8) ui2 { unsigned x, y; };

// log2(e) / (sqrt(64) + 1e-6)  -- folded into W_q at prep time
#define CEXP (1.44269504089f / (8.0f + 1e-6f))

// ---------- helpers ----------
__device__ __forceinline__ u16 f2bf(float f) {
  unsigned u = __builtin_bit_cast(unsigned, f);
  unsigned r = (u + 0x7FFFu + ((u >> 16) & 1u)) >> 16;  // RNE
  return (u16)r;
}
__device__ __forceinline__ float bf2f(u16 v) {
  return __builtin_bit_cast(float, (unsigned)v << 16);
}

// truncation pack: {bf16(b)[hi16] , bf16(a)[lo16]} in ONE v_perm_b32
__device__ __forceinline__ unsigned pack_bf2_trunc(float a, float b) {
  return __builtin_amdgcn_perm(__builtin_bit_cast(unsigned, b),
                               __builtin_bit_cast(unsigned, a), 0x07060302u);
}

__device__ __forceinline__ void async_load16(const void* g, void* l) {
  __builtin_amdgcn_global_load_lds((const __attribute__((address_space(1))) void*)g,
                                   (__attribute__((address_space(3))) void*)l, 16, 0, 0);
}

// ---------- weight prep: LDS-tile transpose (both sides coalesced) ----------
// wqkvT: [1536,512] bf16 (rows 0-511 = Wq^T*CEXP, 512-1023 = Wk^T, 1024-1535 = Wv^T)
__global__ void prep_weights(const float* __restrict__ Wq, const float* __restrict__ Wk,
                             const float* __restrict__ Wv, const float* __restrict__ Wo,
                             const float* __restrict__ w1, const float* __restrict__ w2,
                             u16* __restrict__ wqkvT, u16* __restrict__ woT,
                             u16* __restrict__ w1b, u16* __restrict__ w2b) {
  const int z = blockIdx.y;
  const int t = threadIdx.x;
  if (z < 4) {
    const float* src = z == 0 ? Wq : z == 1 ? Wk : z == 2 ? Wv : Wo;
    u16* dst = z < 3 ? wqkvT + z * 512 * 512 : woT;
    const float scale = (z == 0) ? CEXP : 1.0f;
    __shared__ float tl[64][65];
    const int ti = blockIdx.x >> 3, tj = blockIdx.x & 7;
    const int tx = t & 15, ty = t >> 4;
#pragma unroll
    for (int rr = 0; rr < 4; rr++) {
      const int row = rr * 16 + ty;
      float4 v = *(const float4*)&src[(size_t)(ti * 64 + row) * 512 + tj * 64 + tx * 4];
      tl[row][tx * 4 + 0] = v.x; tl[row][tx * 4 + 1] = v.y;
      tl[row][tx * 4 + 2] = v.z; tl[row][tx * 4 + 3] = v.w;
    }
    __syncthreads();
#pragma unroll
    for (int rr = 0; rr < 4; rr++) {
      const int row = rr * 16 + ty;
      us4 o;
      o.x = f2bf(tl[tx * 4 + 0][row] * scale);
      o.y = f2bf(tl[tx * 4 + 1][row] * scale);
      o.z = f2bf(tl[tx * 4 + 2][row] * scale);
      o.w = f2bf(tl[tx * 4 + 3][row] * scale);
      *(us4*)&dst[(size_t)(tj * 64 + row) * 512 + ti * 64 + tx * 4] = o;
    }
  } else {
    const float* src = z == 4 ? w1 : w2;
    u16* dst = z == 4 ? w1b : w2b;
    const int stride = gridDim.x * blockDim.x;
    for (int i = blockIdx.x * blockDim.x + t; i < 2048 * 512 / 4; i += stride) {
      float4 v = ((const float4*)src)[i];
      us4 o;
      o.x = f2bf(v.x); o.y = f2bf(v.y); o.z = f2bf(v.z); o.w = f2bf(v.w);
      ((us4*)dst)[i] = o;
    }
  }
}

// ---------- LayerNorm row kernel (+ optional bf16 cast of K,V rows) ----------
template <bool KV>
__launch_bounds__(128)
__global__ void ln_cast(const float* __restrict__ X, const float* __restrict__ gw,
                        const float* __restrict__ bw, u16* __restrict__ Y,
                        const float* __restrict__ Kin, const float* __restrict__ Vin,
                        u16* __restrict__ Kb, u16* __restrict__ Vb) {
  const int row = blockIdx.x, t = threadIdx.x;
  const size_t base = (size_t)row * 512;
  float4 x = ((const float4*)(X + base))[t];
  float s = x.x + x.y + x.z + x.w;
  float ss = x.x * x.x + x.y * x.y + x.z * x.z + x.w * x.w;
#pragma unroll
  for (int off = 32; off > 0; off >>= 1) {
    s += __shfl_xor(s, off);
    ss += __shfl_xor(ss, off);
  }
  __shared__ float red[4];
  if ((t & 63) == 0) { red[(t >> 6) * 2] = s; red[(t >> 6) * 2 + 1] = ss; }
  __syncthreads();
  const float tot = red[0] + red[2], tss = red[1] + red[3];
  const float mu = tot * (1.0f / 512.0f);
  const float var = tss * (1.0f / 512.0f) - mu * mu;
  const float rs = rsqrtf(var + 1e-5f);
  float4 g4 = ((const float4*)gw)[t];
  float4 b4 = ((const float4*)bw)[t];
  us4 o;
  o.x = f2bf((x.x - mu) * rs * g4.x + b4.x);
  o.y = f2bf((x.y - mu) * rs * g4.y + b4.y);
  o.z = f2bf((x.z - mu) * rs * g4.z + b4.z);
  o.w = f2bf((x.w - mu) * rs * g4.w + b4.w);
  ((us4*)(Y + base))[t] = o;
  if constexpr (KV) {
    float4 k4 = ((const float4*)(Kin + base))[t];
    float4 v4 = ((const float4*)(Vin + base))[t];
    us4 ko, vo;
    ko.x = f2bf(k4.x); ko.y = f2bf(k4.y); ko.z = f2bf(k4.z); ko.w = f2bf(k4.w);
    vo.x = f2bf(v4.x); vo.y = f2bf(v4.y); vo.z = f2bf(v4.z); vo.w = f2bf(v4.w);
    ((us4*)(Kb + base))[t] = ko;
    ((us4*)(Vb + base))[t] = vo;
  }
}

// ---------- merged QKV projection GEMM (XOR-swizzled LDS chunks) ----------
__launch_bounds__(256, 3)
__global__ void gemm_qkv(const u16* __restrict__ Aq, const u16* __restrict__ Ak,
                         const u16* __restrict__ Av, const u16* __restrict__ Bt,
                         u16* __restrict__ qb, u16* __restrict__ kb, u16* __restrict__ vtb) {
  __shared__ __align__(16) u16 sA[128 * 32];
  __shared__ __align__(16) u16 sB[128 * 32];
  const int tid = threadIdx.x;
  const int wave = tid >> 6, lane = tid & 63;
  const int l15 = lane & 15, quad = lane >> 4;
  const int qsw = (quad ^ ((l15 >> 1) & 3)) * 8;
  const int m0 = blockIdx.x * 128, n0 = blockIdx.y * 128;
  const int sel = n0 >> 9;  // 0=q, 1=k, 2=v
  const u16* A = sel == 0 ? Aq : sel == 1 ? Ak : Av;
  const int wm = (wave >> 1) * 64, wn = (wave & 1) * 64;
  const int u0 = wave * 64 + lane, u1 = u0 + 256;
  const int sw0 = ((u0 & 3) ^ ((u0 >> 3) & 3)) * 8;  // same for u1
  const int K = 512;

  const u16* a0 = A + (size_t)(m0 + (u0 >> 2)) * K + sw0;
  const u16* a1 = A + (size_t)(m0 + (u1 >> 2)) * K + sw0;
  const u16* b0 = Bt + (size_t)(n0 + (u0 >> 2)) * K + sw0;
  const u16* b1p = Bt + (size_t)(n0 + (u1 >> 2)) * K + sw0;

  f32x4 acc[4][4] = {};
  for (int k0 = 0; k0 < K; k0 += 32) {
    async_load16(a0 + k0, &sA[wave * 512]);
    async_load16(a1 + k0, &sA[2048 + wave * 512]);
    async_load16(b0 + k0, &sB[wave * 512]);
    async_load16(b1p + k0, &sB[2048 + wave * 512]);
    __syncthreads();
    short8 af[4], bfr[4];
#pragma unroll
    for (int i = 0; i < 4; i++)
      af[i] = *(const short8*)&sA[(wm + i * 16 + l15) * 32 + qsw];
#pragma unroll
    for (int j = 0; j < 4; j++)
      bfr[j] = *(const short8*)&sB[(wn + j * 16 + l15) * 32 + qsw];
#pragma unroll
    for (int i = 0; i < 4; i++)
#pragma unroll
      for (int j = 0; j < 4; j++)
        acc[i][j] = __builtin_amdgcn_mfma_f32_16x16x32_bf16(af[i], bfr[j], acc[i][j], 0, 0, 0);
    __syncthreads();
  }

#pragma unroll
  for (int i = 0; i < 4; i++) {
#pragma unroll
    for (int j = 0; j < 4; j++) {
      const int ocol = ((n0 + wn) & 511) + j * 16 + l15;
      const int row0 = m0 + wm + i * 16 + quad * 4;
      if (sel < 2) {
        u16* C = sel == 0 ? qb : kb;
#pragma unroll
        for (int r = 0; r < 4; r++) C[(size_t)(row0 + r) * 512 + ocol] = f2bf(acc[i][j][r]);
      } else {
        const int b = row0 >> 12, s0 = row0 & 4095;
        const int hh = ocol >> 6, cc = ocol & 63;
        us4 pk;
        pk.x = f2bf(acc[i][j][0]); pk.y = f2bf(acc[i][j][1]);
        pk.z = f2bf(acc[i][j][2]); pk.w = f2bf(acc[i][j][3]);
        *(us4*)&vtb[((size_t)((b * 8 + hh) * 64 + cc) << 12) + s0] = pk;
      }
    }
  }
}

// ---------- GEMM: C[M,N] = A[M,K] @ Bt[N,K]^T (XOR-swizzled LDS chunks) ----------
// EP: 2 = fp32 store + res add | 3 = +bias, exact GELU, bf16 | 4 = +bias +res, fp32
template <int EP, int TN, int LB>
__launch_bounds__(256, LB)
__global__ void gemm_bt(const u16* __restrict__ A, const u16* __restrict__ Bt,
                        int M, int N, int K, void* __restrict__ Cp,
                        const float* __restrict__ bias, const float* __restrict__ res) {
  constexpr int MI = (TN == 128) ? 4 : 2;
  __shared__ __align__(16) u16 sA[128 * 32];
  __shared__ __align__(16) u16 sB[TN * 32];
  const int tid = threadIdx.x;
  const int wave = tid >> 6, lane = tid & 63;
  const int l15 = lane & 15, quad = lane >> 4;
  const int qsw = (quad ^ ((l15 >> 1) & 3)) * 8;
  const int m0 = blockIdx.x * 128, n0 = blockIdx.y * TN;
  const int wm = (TN == 128) ? (wave >> 1) * 64 : wave * 32;
  const int wn = (TN == 128) ? (wave & 1) * 64 : 0;
  const int u0 = wave * 64 + lane, u1 = u0 + 256;
  const int sw0 = ((u0 & 3) ^ ((u0 >> 3) & 3)) * 8;

  const u16* a0 = A + (size_t)(m0 + (u0 >> 2)) * K + sw0;
  const u16* a1 = A + (size_t)(m0 + (u1 >> 2)) * K + sw0;
  const u16* b0 = Bt + (size_t)(n0 + (u0 >> 2)) * K + sw0;

  f32x4 acc[MI][4] = {};
  for (int k0 = 0; k0 < K; k0 += 32) {
    async_load16(a0 + k0, &sA[wave * 512]);
    async_load16(a1 + k0, &sA[2048 + wave * 512]);
    async_load16(b0 + k0, &sB[wave * 512]);
    if constexpr (TN == 128) {
      const u16* b1p = Bt + (size_t)(n0 + (u1 >> 2)) * K + sw0;
      async_load16(b1p + k0, &sB[2048 + wave * 512]);
    }
    __syncthreads();
    short8 af[MI], bfr[4];
#pragma unroll
    for (int i = 0; i < MI; i++)
      af[i] = *(const short8*)&sA[(wm + i * 16 + l15) * 32 + qsw];
#pragma unroll
    for (int j = 0; j < 4; j++)
      bfr[j] = *(const short8*)&sB[(wn + j * 16 + l15) * 32 + qsw];
#pragma unroll
    for (int i = 0; i < MI; i++)
#pragma unroll
      for (int j = 0; j < 4; j++)
        acc[i][j] = __builtin_amdgcn_mfma_f32_16x16x32_bf16(af[i], bfr[j], acc[i][j], 0, 0, 0);
    __syncthreads();
  }

#pragma unroll
  for (int i = 0; i < MI; i++) {
#pragma unroll
    for (int j = 0; j < 4; j++) {
      const int col = n0 + wn + j * 16 + l15;
      const int row0 = m0 + wm + i * 16 + quad * 4;
      if (EP == 2) {
        float* C = (float*)Cp;
#pragma unroll
        for (int r = 0; r < 4; r++) {
          size_t idx = (size_t)(row0 + r) * N + col;
          C[idx] = acc[i][j][r] + res[idx];
        }
      } else if (EP == 3) {
        u16* C = (u16*)Cp;
        const float bv = bias[col];
#pragma unroll
        for (int r = 0; r < 4; r++) {
          float xx = acc[i][j][r] + bv;
          float gl = 0.5f * xx * (1.0f + erff(xx * 0.70710678118f));
          C[(size_t)(row0 + r) * N + col] = f2bf(gl);
        }
      } else {
        float* C = (float*)Cp;
        const float bv = bias[col];
#pragma unroll
        for (int r = 0; r < 4; r++) {
          size_t idx = (size_t)(row0 + r) * N + col;
          C[idx] = acc[i][j][r] + bv + res[idx];
        }
      }
    }
  }
}

// ---------- flash attention, mi=4 (64 q/wave), split-K=4 ----------
// grid (S/256, B*H, 4).  4 waves x 64 q-rows; each z-slice covers 1024 keys.
// St = K·Q^T; no running max (scores bounded, scale in Wq) => partials sum.
// po: [4][8192][512] bf16 unnormalized O;  pl: [4][8192*8] fp32 l sums.
__launch_bounds__(256, 3)
__global__ void attn_kernel(const u16* __restrict__ qb, const u16* __restrict__ kb,
                            const u16* __restrict__ vtb, u16* __restrict__ po,
                            float* __restrict__ pl) {
  __shared__ __align__(16) u16 sK[2 * 128 * 32];   // 16 KB
  __shared__ __align__(16) u16 sV[4 * 64 * 32];    // 16 KB
  __shared__ __align__(16) u16 sP[4 * 64 * 40];    // 20 KB (per-wave [64 q][40])
  const int tid = threadIdx.x;
  const int wave = tid >> 6, lane = tid & 63;
  const int l15 = lane & 15, quad = lane >> 4;
  const int qsw = (quad ^ ((l15 >> 1) & 3)) * 8;
  const int bh = blockIdx.y, b = bh >> 3, h = bh & 7;
  const int q0 = blockIdx.x * 256;
  const int ks = blockIdx.z;
  const size_t rb = (size_t)b * 4096;

  short8 qf[4][2];
#pragma unroll
  for (int mi = 0; mi < 4; mi++)
#pragma unroll
    for (int kk = 0; kk < 2; kk++) {
      int row = q0 + wave * 64 + mi * 16 + l15;
      qf[mi][kk] = *(const short8*)&qb[(rb + row) * 512 + h * 64 + kk * 32 + quad * 8];
    }

  f32x4 o_t[4][4] = {};
  float l_part[4] = {0.f, 0.f, 0.f, 0.f};
  u16* myP = &sP[wave * 64 * 40];

  for (int jt = 0; jt < 8; jt++) {
    const int j0 = ks * 1024 + jt * 128;
#pragma unroll
    for (int r = 0; r < 4; r++) {
      int u = r * 256 + wave * 64 + lane;
      int kk = u >> 9, key = (u >> 2) & 127, c8 = (u & 3) ^ ((u >> 3) & 3);
      async_load16(&kb[(rb + j0 + key) * 512 + h * 64 + kk * 32 + c8 * 8],
                   &sK[(r * 256 + wave * 64) * 8]);
    }
#pragma unroll
    for (int r = 0; r < 4; r++) {
      int u = r * 256 + wave * 64 + lane;
      int kk = u >> 8, vc = (u >> 2) & 63, c8 = (u & 3) ^ ((u >> 3) & 3);
      async_load16(&vtb[((size_t)(bh * 64 + vc)) * 4096 + j0 + kk * 32 + c8 * 8],
                   &sV[(r * 256 + wave * 64) * 8]);
    }
    __syncthreads();

#pragma unroll
    for (int kk = 0; kk < 4; kk++) {
#pragma unroll
      for (int nh = 0; nh < 2; nh++) {
        const int ni = kk * 2 + nh;
        short8 af0 = *(const short8*)&sK[(ni * 16 + l15) * 32 + qsw];
        short8 af1 = *(const short8*)&sK[4096 + (ni * 16 + l15) * 32 + qsw];
#pragma unroll
        for (int mi = 0; mi < 4; mi++) {
          f32x4 st = {};
          st = __builtin_amdgcn_mfma_f32_16x16x32_bf16(af0, qf[mi][0], st, 0, 0, 0);
          st = __builtin_amdgcn_mfma_f32_16x16x32_bf16(af1, qf[mi][1], st, 0, 0, 0);
          float p0 = __builtin_amdgcn_exp2f(st[0]);
          float p1 = __builtin_amdgcn_exp2f(st[1]);
          float p2 = __builtin_amdgcn_exp2f(st[2]);
          float p3 = __builtin_amdgcn_exp2f(st[3]);
          l_part[mi] += (p0 + p1) + (p2 + p3);
          ui2 wv;
          wv.x = pack_bf2_trunc(p0, p1);
          wv.y = pack_bf2_trunc(p2, p3);
          *(ui2*)&myP[(mi * 16 + l15) * 40 + nh * 16 + quad * 4] = wv;
        }
      }
      asm volatile("s_waitcnt lgkmcnt(0)" ::: "memory");
      short8 pf[4], vf[4];
#pragma unroll
      for (int mi = 0; mi < 4; mi++)
        pf[mi] = *(const short8*)&myP[(mi * 16 + l15) * 40 + quad * 8];
#pragma unroll
      for (int vi = 0; vi < 4; vi++)
        vf[vi] = *(const short8*)&sV[kk * 2048 + (vi * 16 + l15) * 32 + qsw];
#pragma unroll
      for (int mi = 0; mi < 4; mi++)
#pragma unroll
        for (int vi = 0; vi < 4; vi++)
          o_t[mi][vi] = __builtin_amdgcn_mfma_f32_16x16x32_bf16(vf[vi], pf[mi], o_t[mi][vi], 0, 0, 0);
    }
    __syncthreads();
  }

#pragma unroll
  for (int mi = 0; mi < 4; mi++) {
    float l = l_part[mi];
    l += __shfl_xor(l, 16);
    l += __shfl_xor(l, 32);
    const int qrow = q0 + wave * 64 + mi * 16 + l15;
    if (quad == 0) pl[(size_t)ks * 65536 + (rb + qrow) * 8 + h] = l;
#pragma unroll
    for (int vi = 0; vi < 4; vi++) {
      us4 o;
      o.x = f2bf(o_t[mi][vi][0]); o.y = f2bf(o_t[mi][vi][1]);
      o.z = f2bf(o_t[mi][vi][2]); o.w = f2bf(o_t[mi][vi][3]);
      *(us4*)&po[(size_t)ks * 4194304 + (rb + qrow) * 512 + h * 64 + vi * 16 + quad * 4] = o;
    }
  }
}

// ---------- merge 4 split-K partials -> ctx bf16 ----------
__launch_bounds__(128)
__global__ void attn_merge(const u16* __restrict__ po, const float* __restrict__ pl,
                           u16* __restrict__ ctx) {
  const int row = blockIdx.x, t = threadIdx.x;
  const int col = t * 4, h = col >> 6;
  const size_t idx = (size_t)row * 512 + col;
  float l = 0.f;
#pragma unroll
  for (int ks = 0; ks < 4; ks++) l += pl[(size_t)ks * 65536 + row * 8 + h];
  float o0 = 0.f, o1 = 0.f, o2 = 0.f, o3 = 0.f;
#pragma unroll
  for (int ks = 0; ks < 4; ks++) {
    us4 v = *(const us4*)&po[(size_t)ks * 4194304 + idx];
    o0 += bf2f(v.x); o1 += bf2f(v.y); o2 += bf2f(v.z); o3 += bf2f(v.w);
  }
  const float inv = 1.0f / l;
  us4 o;
  o.x = f2bf(o0 * inv); o.y = f2bf(o1 * inv);
  o.z = f2bf(o2 * inv); o.w = f2bf(o3 * inv);
  *(us4*)&ctx[idx] = o;
}

// ---------- launch ----------
extern "C" void kernel_launch(void* const* d_in, const int* in_sizes, int n_in,
                              void* d_out, int out_size, void* d_ws, size_t ws_size,
                              hipStream_t stream) {
  (void)in_sizes; (void)n_in; (void)out_size; (void)ws_size;
  const float* Q = (const float*)d_in[0];
  const float* K = (const float*)d_in[1];
  const float* V = (const float*)d_in[2];
  const float* W_q = (const float*)d_in[3];
  const float* W_k = (const float*)d_in[4];
  const float* W_v = (const float*)d_in[5];
  const float* W_o = (const float*)d_in[6];
  const float* ln1_g = (const float*)d_in[7];
  const float* ln1_b = (const float*)d_in[8];
  const float* ln2_g = (const float*)d_in[9];
  const float* ln2_b = (const float*)d_in[10];
  const float* w1 = (const float*)d_in[11];
  const float* b1 = (const float*)d_in[12];
  const float* w2 = (const float*)d_in[13];
  const float* b2 = (const float*)d_in[14];

  char* w = (char*)d_ws;
  const size_t MB = 1u << 20;
  // weights: [0,6) MB
  u16* wqkvT = (u16*)(w);                       // 1.5 MB [1536,512]
  u16* woT = (u16*)(w + 3 * MB / 2);            // 0.5 MB
  u16* w1b = (u16*)(w + 2 * MB);                // 2 MB
  u16* w2b = (u16*)(w + 4 * MB);                // 2 MB
  u16* Qn  = (u16*)(w + 6 * MB);                // [6,14)  bf16 LN1(Q); pl lives at [6,7) after qkv
  u16* Kb  = (u16*)(w + 14 * MB);               // [14,22) bf16 K
  u16* Vb  = (u16*)(w + 22 * MB);               // [22,30) bf16 V
  u16* qb  = (u16*)(w + 30 * MB);               // [30,38)
  u16* kb  = (u16*)(w + 38 * MB);               // [38,46)
  u16* vtb = (u16*)(w + 46 * MB);               // [46,54)
  u16* ctx = (u16*)(w + 54 * MB);               // [54,62)
  u16* po  = (u16*)(w + 62 * MB);               // [62,94) 4 x 8 MB bf16 partial O
  float* pl = (float*)(w + 6 * MB);             // 1 MB in Qn region (dead after qkv)
  float* X = (float*)(w + 94 * MB);             // [94,110) fp32 X = Q + attn_out
  u16* Xn  = (u16*)(w + 6 * MB);                // reuse Qn region (after merge)
  u16* hb  = (u16*)(w + 14 * MB);               // [14,46) 32 MB (dead after attn)

  prep_weights<<<dim3(64, 6), 256, 0, stream>>>(W_q, W_k, W_v, W_o, w1, w2,
                                                wqkvT, woT, w1b, w2b);
  ln_cast<true><<<8192, 128, 0, stream>>>(Q, ln1_g, ln1_b, Qn, K, V, Kb, Vb);
  gemm_qkv<<<dim3(64, 12), 256, 0, stream>>>(Qn, Kb, Vb, wqkvT, qb, kb, vtb);
  attn_kernel<<<dim3(16, 16, 4), 256, 0, stream>>>(qb, kb, vtb, po, pl);
  attn_merge<<<8192, 128, 0, stream>>>(po, pl, ctx);
  gemm_bt<2, 64, 3><<<dim3(64, 8), 256, 0, stream>>>(ctx, woT, 8192, 512, 512, X, nullptr, Q);
  ln_cast<false><<<8192, 128, 0, stream>>>(X, ln2_g, ln2_b, Xn, nullptr, nullptr, nullptr, nullptr);
  gemm_bt<3, 128, 3><<<dim3(64, 16), 256, 0, stream>>>(Xn, w1b, 8192, 2048, 512, hb, b1, nullptr);
  gemm_bt<4, 64, 3><<<dim3(64, 8), 256, 0, stream>>>(hb, w2b, 8192, 512, 2048, (float*)d_out, b2, X);
}

// Round 7
// 344.523 us; speedup vs baseline: 1.1977x; 1.1977x over previous
//
#include <hip/hip_runtime.h>

typedef unsigned short u16;
typedef __attribute__((ext_vector_type(8))) short short8;
typedef __attribute__((ext_vector_type(4))) float f32x4;

struct __align__(8) us4 { u16 x, y, z, w; };
struct __align__(8) ui2 { unsigned x, y; };

// log2(e) / (sqrt(64) + 1e-6)  -- folded into W_q at prep time
#define CEXP (1.44269504089f / (8.0f + 1e-6f))

// ---------- helpers ----------
__device__ __forceinline__ u16 f2bf(float f) {
  unsigned u = __builtin_bit_cast(unsigned, f);
  unsigned r = (u + 0x7FFFu + ((u >> 16) & 1u)) >> 16;  // RNE
  return (u16)r;
}

// truncation pack: {bf16(b)[hi16] , bf16(a)[lo16]} in ONE v_perm_b32
__device__ __forceinline__ unsigned pack_bf2_trunc(float a, float b) {
  return __builtin_amdgcn_perm(__builtin_bit_cast(unsigned, b),
                               __builtin_bit_cast(unsigned, a), 0x07060302u);
}

__device__ __forceinline__ void async_load16(const void* g, void* l) {
  __builtin_amdgcn_global_load_lds((const __attribute__((address_space(1))) void*)g,
                                   (__attribute__((address_space(3))) void*)l, 16, 0, 0);
}

// ---------- weight prep: LDS-tile transpose (both sides coalesced) ----------
// wqkvT: [1536,512] bf16 (rows 0-511 = Wq^T*CEXP, 512-1023 = Wk^T, 1024-1535 = Wv^T)
__global__ void prep_weights(const float* __restrict__ Wq, const float* __restrict__ Wk,
                             const float* __restrict__ Wv, const float* __restrict__ Wo,
                             const float* __restrict__ w1, const float* __restrict__ w2,
                             u16* __restrict__ wqkvT, u16* __restrict__ woT,
                             u16* __restrict__ w1b, u16* __restrict__ w2b) {
  const int z = blockIdx.y;
  const int t = threadIdx.x;
  if (z < 4) {
    const float* src = z == 0 ? Wq : z == 1 ? Wk : z == 2 ? Wv : Wo;
    u16* dst = z < 3 ? wqkvT + z * 512 * 512 : woT;
    const float scale = (z == 0) ? CEXP : 1.0f;
    __shared__ float tl[64][65];
    const int ti = blockIdx.x >> 3, tj = blockIdx.x & 7;
    const int tx = t & 15, ty = t >> 4;
#pragma unroll
    for (int rr = 0; rr < 4; rr++) {
      const int row = rr * 16 + ty;
      float4 v = *(const float4*)&src[(size_t)(ti * 64 + row) * 512 + tj * 64 + tx * 4];
      tl[row][tx * 4 + 0] = v.x; tl[row][tx * 4 + 1] = v.y;
      tl[row][tx * 4 + 2] = v.z; tl[row][tx * 4 + 3] = v.w;
    }
    __syncthreads();
#pragma unroll
    for (int rr = 0; rr < 4; rr++) {
      const int row = rr * 16 + ty;
      us4 o;
      o.x = f2bf(tl[tx * 4 + 0][row] * scale);
      o.y = f2bf(tl[tx * 4 + 1][row] * scale);
      o.z = f2bf(tl[tx * 4 + 2][row] * scale);
      o.w = f2bf(tl[tx * 4 + 3][row] * scale);
      *(us4*)&dst[(size_t)(tj * 64 + row) * 512 + ti * 64 + tx * 4] = o;
    }
  } else {
    const float* src = z == 4 ? w1 : w2;
    u16* dst = z == 4 ? w1b : w2b;
    const int stride = gridDim.x * blockDim.x;
    for (int i = blockIdx.x * blockDim.x + t; i < 2048 * 512 / 4; i += stride) {
      float4 v = ((const float4*)src)[i];
      us4 o;
      o.x = f2bf(v.x); o.y = f2bf(v.y); o.z = f2bf(v.z); o.w = f2bf(v.w);
      ((us4*)dst)[i] = o;
    }
  }
}

// ---------- LayerNorm row kernel (+ optional bf16 cast of K,V rows) ----------
template <bool KV>
__launch_bounds__(128)
__global__ void ln_cast(const float* __restrict__ X, const float* __restrict__ gw,
                        const float* __restrict__ bw, u16* __restrict__ Y,
                        const float* __restrict__ Kin, const float* __restrict__ Vin,
                        u16* __restrict__ Kb, u16* __restrict__ Vb) {
  const int row = blockIdx.x, t = threadIdx.x;
  const size_t base = (size_t)row * 512;
  float4 x = ((const float4*)(X + base))[t];
  float s = x.x + x.y + x.z + x.w;
  float ss = x.x * x.x + x.y * x.y + x.z * x.z + x.w * x.w;
#pragma unroll
  for (int off = 32; off > 0; off >>= 1) {
    s += __shfl_xor(s, off);
    ss += __shfl_xor(ss, off);
  }
  __shared__ float red[4];
  if ((t & 63) == 0) { red[(t >> 6) * 2] = s; red[(t >> 6) * 2 + 1] = ss; }
  __syncthreads();
  const float tot = red[0] + red[2], tss = red[1] + red[3];
  const float mu = tot * (1.0f / 512.0f);
  const float var = tss * (1.0f / 512.0f) - mu * mu;
  const float rs = rsqrtf(var + 1e-5f);
  float4 g4 = ((const float4*)gw)[t];
  float4 b4 = ((const float4*)bw)[t];
  us4 o;
  o.x = f2bf((x.x - mu) * rs * g4.x + b4.x);
  o.y = f2bf((x.y - mu) * rs * g4.y + b4.y);
  o.z = f2bf((x.z - mu) * rs * g4.z + b4.z);
  o.w = f2bf((x.w - mu) * rs * g4.w + b4.w);
  ((us4*)(Y + base))[t] = o;
  if constexpr (KV) {
    float4 k4 = ((const float4*)(Kin + base))[t];
    float4 v4 = ((const float4*)(Vin + base))[t];
    us4 ko, vo;
    ko.x = f2bf(k4.x); ko.y = f2bf(k4.y); ko.z = f2bf(k4.z); ko.w = f2bf(k4.w);
    vo.x = f2bf(v4.x); vo.y = f2bf(v4.y); vo.z = f2bf(v4.z); vo.w = f2bf(v4.w);
    ((us4*)(Kb + base))[t] = ko;
    ((us4*)(Vb + base))[t] = vo;
  }
}

// ---------- merged QKV projection GEMM (XOR-swizzled LDS chunks) ----------
__launch_bounds__(256, 3)
__global__ void gemm_qkv(const u16* __restrict__ Aq, const u16* __restrict__ Ak,
                         const u16* __restrict__ Av, const u16* __restrict__ Bt,
                         u16* __restrict__ qb, u16* __restrict__ kb, u16* __restrict__ vtb) {
  __shared__ __align__(16) u16 sA[128 * 32];
  __shared__ __align__(16) u16 sB[128 * 32];
  const int tid = threadIdx.x;
  const int wave = tid >> 6, lane = tid & 63;
  const int l15 = lane & 15, quad = lane >> 4;
  const int qsw = (quad ^ ((l15 >> 1) & 3)) * 8;
  const int m0 = blockIdx.x * 128, n0 = blockIdx.y * 128;
  const int sel = n0 >> 9;  // 0=q, 1=k, 2=v
  const u16* A = sel == 0 ? Aq : sel == 1 ? Ak : Av;
  const int wm = (wave >> 1) * 64, wn = (wave & 1) * 64;
  const int u0 = wave * 64 + lane, u1 = u0 + 256;
  const int sw0 = ((u0 & 3) ^ ((u0 >> 3) & 3)) * 8;  // same for u1
  const int K = 512;

  const u16* a0 = A + (size_t)(m0 + (u0 >> 2)) * K + sw0;
  const u16* a1 = A + (size_t)(m0 + (u1 >> 2)) * K + sw0;
  const u16* b0 = Bt + (size_t)(n0 + (u0 >> 2)) * K + sw0;
  const u16* b1p = Bt + (size_t)(n0 + (u1 >> 2)) * K + sw0;

  f32x4 acc[4][4] = {};
  for (int k0 = 0; k0 < K; k0 += 32) {
    async_load16(a0 + k0, &sA[wave * 512]);
    async_load16(a1 + k0, &sA[2048 + wave * 512]);
    async_load16(b0 + k0, &sB[wave * 512]);
    async_load16(b1p + k0, &sB[2048 + wave * 512]);
    __syncthreads();
    short8 af[4], bfr[4];
#pragma unroll
    for (int i = 0; i < 4; i++)
      af[i] = *(const short8*)&sA[(wm + i * 16 + l15) * 32 + qsw];
#pragma unroll
    for (int j = 0; j < 4; j++)
      bfr[j] = *(const short8*)&sB[(wn + j * 16 + l15) * 32 + qsw];
#pragma unroll
    for (int i = 0; i < 4; i++)
#pragma unroll
      for (int j = 0; j < 4; j++)
        acc[i][j] = __builtin_amdgcn_mfma_f32_16x16x32_bf16(af[i], bfr[j], acc[i][j], 0, 0, 0);
    __syncthreads();
  }

#pragma unroll
  for (int i = 0; i < 4; i++) {
#pragma unroll
    for (int j = 0; j < 4; j++) {
      const int ocol = ((n0 + wn) & 511) + j * 16 + l15;
      const int row0 = m0 + wm + i * 16 + quad * 4;
      if (sel < 2) {
        u16* C = sel == 0 ? qb : kb;
#pragma unroll
        for (int r = 0; r < 4; r++) C[(size_t)(row0 + r) * 512 + ocol] = f2bf(acc[i][j][r]);
      } else {
        const int b = row0 >> 12, s0 = row0 & 4095;
        const int hh = ocol >> 6, cc = ocol & 63;
        us4 pk;
        pk.x = f2bf(acc[i][j][0]); pk.y = f2bf(acc[i][j][1]);
        pk.z = f2bf(acc[i][j][2]); pk.w = f2bf(acc[i][j][3]);
        *(us4*)&vtb[((size_t)((b * 8 + hh) * 64 + cc) << 12) + s0] = pk;
      }
    }
  }
}

// ---------- GEMM: C[M,N] = A[M,K] @ Bt[N,K]^T (XOR-swizzled LDS chunks) ----------
// EP: 2 = fp32 store + res add | 3 = +bias, exact GELU, bf16 | 4 = +bias +res, fp32
template <int EP, int TN, int LB>
__launch_bounds__(256, LB)
__global__ void gemm_bt(const u16* __restrict__ A, const u16* __restrict__ Bt,
                        int M, int N, int K, void* __restrict__ Cp,
                        const float* __restrict__ bias, const float* __restrict__ res) {
  constexpr int MI = (TN == 128) ? 4 : 2;
  __shared__ __align__(16) u16 sA[128 * 32];
  __shared__ __align__(16) u16 sB[TN * 32];
  const int tid = threadIdx.x;
  const int wave = tid >> 6, lane = tid & 63;
  const int l15 = lane & 15, quad = lane >> 4;
  const int qsw = (quad ^ ((l15 >> 1) & 3)) * 8;
  const int m0 = blockIdx.x * 128, n0 = blockIdx.y * TN;
  const int wm = (TN == 128) ? (wave >> 1) * 64 : wave * 32;
  const int wn = (TN == 128) ? (wave & 1) * 64 : 0;
  const int u0 = wave * 64 + lane, u1 = u0 + 256;
  const int sw0 = ((u0 & 3) ^ ((u0 >> 3) & 3)) * 8;

  const u16* a0 = A + (size_t)(m0 + (u0 >> 2)) * K + sw0;
  const u16* a1 = A + (size_t)(m0 + (u1 >> 2)) * K + sw0;
  const u16* b0 = Bt + (size_t)(n0 + (u0 >> 2)) * K + sw0;

  f32x4 acc[MI][4] = {};
  for (int k0 = 0; k0 < K; k0 += 32) {
    async_load16(a0 + k0, &sA[wave * 512]);
    async_load16(a1 + k0, &sA[2048 + wave * 512]);
    async_load16(b0 + k0, &sB[wave * 512]);
    if constexpr (TN == 128) {
      const u16* b1p = Bt + (size_t)(n0 + (u1 >> 2)) * K + sw0;
      async_load16(b1p + k0, &sB[2048 + wave * 512]);
    }
    __syncthreads();
    short8 af[MI], bfr[4];
#pragma unroll
    for (int i = 0; i < MI; i++)
      af[i] = *(const short8*)&sA[(wm + i * 16 + l15) * 32 + qsw];
#pragma unroll
    for (int j = 0; j < 4; j++)
      bfr[j] = *(const short8*)&sB[(wn + j * 16 + l15) * 32 + qsw];
#pragma unroll
    for (int i = 0; i < MI; i++)
#pragma unroll
      for (int j = 0; j < 4; j++)
        acc[i][j] = __builtin_amdgcn_mfma_f32_16x16x32_bf16(af[i], bfr[j], acc[i][j], 0, 0, 0);
    __syncthreads();
  }

#pragma unroll
  for (int i = 0; i < MI; i++) {
#pragma unroll
    for (int j = 0; j < 4; j++) {
      const int col = n0 + wn + j * 16 + l15;
      const int row0 = m0 + wm + i * 16 + quad * 4;
      if (EP == 2) {
        float* C = (float*)Cp;
#pragma unroll
        for (int r = 0; r < 4; r++) {
          size_t idx = (size_t)(row0 + r) * N + col;
          C[idx] = acc[i][j][r] + res[idx];
        }
      } else if (EP == 3) {
        u16* C = (u16*)Cp;
        const float bv = bias[col];
#pragma unroll
        for (int r = 0; r < 4; r++) {
          float xx = acc[i][j][r] + bv;
          float gl = 0.5f * xx * (1.0f + erff(xx * 0.70710678118f));
          C[(size_t)(row0 + r) * N + col] = f2bf(gl);
        }
      } else {
        float* C = (float*)Cp;
        const float bv = bias[col];
#pragma unroll
        for (int r = 0; r < 4; r++) {
          size_t idx = (size_t)(row0 + r) * N + col;
          C[idx] = acc[i][j][r] + bv + res[idx];
        }
      }
    }
  }
}

// ---------- flash attention, split-K=2 (R5 config: q-tile 128, mi=2) ----------
// grid (S/128, B*H, 2).  4 waves x 32 q-rows; each z-slice covers 2048 keys.
// St = K·Q^T; no running max (scores bounded, scale in Wq) => partials sum.
// po: [2][8192][512] fp32 unnormalized O;  pl: [2][8192*8] fp32 l sums.
__launch_bounds__(256, 3)
__global__ void attn_kernel(const u16* __restrict__ qb, const u16* __restrict__ kb,
                            const u16* __restrict__ vtb, float* __restrict__ po,
                            float* __restrict__ pl) {
  __shared__ __align__(16) u16 sK[2 * 128 * 32];   // 16 KB
  __shared__ __align__(16) u16 sV[4 * 64 * 32];    // 16 KB
  __shared__ __align__(16) u16 sP[4 * 32 * 40];    // 10 KB
  const int tid = threadIdx.x;
  const int wave = tid >> 6, lane = tid & 63;
  const int l15 = lane & 15, quad = lane >> 4;
  const int qsw = (quad ^ ((l15 >> 1) & 3)) * 8;
  const int bh = blockIdx.y, b = bh >> 3, h = bh & 7;
  const int q0 = blockIdx.x * 128;
  const int ks = blockIdx.z;
  const size_t rb = (size_t)b * 4096;

  short8 qf[2][2];
#pragma unroll
  for (int mi = 0; mi < 2; mi++)
#pragma unroll
    for (int kk = 0; kk < 2; kk++) {
      int row = q0 + wave * 32 + mi * 16 + l15;
      qf[mi][kk] = *(const short8*)&qb[(rb + row) * 512 + h * 64 + kk * 32 + quad * 8];
    }

  f32x4 o_t[2][4] = {};
  float l_part[2] = {0.f, 0.f};
  u16* myP = &sP[wave * 32 * 40];

  for (int jt = 0; jt < 16; jt++) {
    const int j0 = ks * 2048 + jt * 128;
#pragma unroll
    for (int r = 0; r < 4; r++) {
      int u = r * 256 + wave * 64 + lane;
      int kk = u >> 9, key = (u >> 2) & 127, c8 = (u & 3) ^ ((u >> 3) & 3);
      async_load16(&kb[(rb + j0 + key) * 512 + h * 64 + kk * 32 + c8 * 8],
                   &sK[(r * 256 + wave * 64) * 8]);
    }
#pragma unroll
    for (int r = 0; r < 4; r++) {
      int u = r * 256 + wave * 64 + lane;
      int kk = u >> 8, vc = (u >> 2) & 63, c8 = (u & 3) ^ ((u >> 3) & 3);
      async_load16(&vtb[((size_t)(bh * 64 + vc)) * 4096 + j0 + kk * 32 + c8 * 8],
                   &sV[(r * 256 + wave * 64) * 8]);
    }
    __syncthreads();

#pragma unroll
    for (int kk = 0; kk < 4; kk++) {
#pragma unroll
      for (int nh = 0; nh < 2; nh++) {
        const int ni = kk * 2 + nh;
        short8 af0 = *(const short8*)&sK[(ni * 16 + l15) * 32 + qsw];
        short8 af1 = *(const short8*)&sK[4096 + (ni * 16 + l15) * 32 + qsw];
#pragma unroll
        for (int mi = 0; mi < 2; mi++) {
          f32x4 st = {};
          st = __builtin_amdgcn_mfma_f32_16x16x32_bf16(af0, qf[mi][0], st, 0, 0, 0);
          st = __builtin_amdgcn_mfma_f32_16x16x32_bf16(af1, qf[mi][1], st, 0, 0, 0);
          float p0 = __builtin_amdgcn_exp2f(st[0]);
          float p1 = __builtin_amdgcn_exp2f(st[1]);
          float p2 = __builtin_amdgcn_exp2f(st[2]);
          float p3 = __builtin_amdgcn_exp2f(st[3]);
          l_part[mi] += (p0 + p1) + (p2 + p3);
          ui2 wv;
          wv.x = pack_bf2_trunc(p0, p1);
          wv.y = pack_bf2_trunc(p2, p3);
          *(ui2*)&myP[(mi * 16 + l15) * 40 + nh * 16 + quad * 4] = wv;
        }
      }
      asm volatile("s_waitcnt lgkmcnt(0)" ::: "memory");
      short8 pf[2], vf[4];
#pragma unroll
      for (int mi = 0; mi < 2; mi++)
        pf[mi] = *(const short8*)&myP[(mi * 16 + l15) * 40 + quad * 8];
#pragma unroll
      for (int vi = 0; vi < 4; vi++)
        vf[vi] = *(const short8*)&sV[kk * 2048 + (vi * 16 + l15) * 32 + qsw];
#pragma unroll
      for (int mi = 0; mi < 2; mi++)
#pragma unroll
        for (int vi = 0; vi < 4; vi++)
          o_t[mi][vi] = __builtin_amdgcn_mfma_f32_16x16x32_bf16(vf[vi], pf[mi], o_t[mi][vi], 0, 0, 0);
    }
    __syncthreads();
  }

#pragma unroll
  for (int mi = 0; mi < 2; mi++) {
    float l = l_part[mi];
    l += __shfl_xor(l, 16);
    l += __shfl_xor(l, 32);
    const int qrow = q0 + wave * 32 + mi * 16 + l15;
    if (quad == 0) pl[(size_t)ks * 65536 + (rb + qrow) * 8 + h] = l;
#pragma unroll
    for (int vi = 0; vi < 4; vi++)
      *(f32x4*)&po[(size_t)ks * 4194304 + (rb + qrow) * 512 + h * 64 + vi * 16 + quad * 4] =
          o_t[mi][vi];
  }
}

// ---------- merge split-K partials -> ctx bf16 ----------
__launch_bounds__(128)
__global__ void attn_merge(const float* __restrict__ po, const float* __restrict__ pl,
                           u16* __restrict__ ctx) {
  const int row = blockIdx.x, t = threadIdx.x;
  const int col = t * 4, h = col >> 6;
  const size_t idx = (size_t)row * 512 + col;
  const float l = pl[row * 8 + h] + pl[65536 + row * 8 + h];
  f32x4 a = *(const f32x4*)&po[idx];
  f32x4 c = *(const f32x4*)&po[4194304 + idx];
  const float inv = 1.0f / l;
  us4 o;
  o.x = f2bf((a[0] + c[0]) * inv);
  o.y = f2bf((a[1] + c[1]) * inv);
  o.z = f2bf((a[2] + c[2]) * inv);
  o.w = f2bf((a[3] + c[3]) * inv);
  *(us4*)&ctx[idx] = o;
}

// ---------- launch ----------
extern "C" void kernel_launch(void* const* d_in, const int* in_sizes, int n_in,
                              void* d_out, int out_size, void* d_ws, size_t ws_size,
                              hipStream_t stream) {
  (void)in_sizes; (void)n_in; (void)out_size; (void)ws_size;
  const float* Q = (const float*)d_in[0];
  const float* K = (const float*)d_in[1];
  const float* V = (const float*)d_in[2];
  const float* W_q = (const float*)d_in[3];
  const float* W_k = (const float*)d_in[4];
  const float* W_v = (const float*)d_in[5];
  const float* W_o = (const float*)d_in[6];
  const float* ln1_g = (const float*)d_in[7];
  const float* ln1_b = (const float*)d_in[8];
  const float* ln2_g = (const float*)d_in[9];
  const float* ln2_b = (const float*)d_in[10];
  const float* w1 = (const float*)d_in[11];
  const float* b1 = (const float*)d_in[12];
  const float* w2 = (const float*)d_in[13];
  const float* b2 = (const float*)d_in[14];

  char* w = (char*)d_ws;
  const size_t MB = 1u << 20;
  // weights: [0,6) MB
  u16* wqkvT = (u16*)(w);                       // 1.5 MB [1536,512]
  u16* woT = (u16*)(w + 3 * MB / 2);            // 0.5 MB
  u16* w1b = (u16*)(w + 2 * MB);                // 2 MB
  u16* w2b = (u16*)(w + 4 * MB);                // 2 MB
  u16* Qn  = (u16*)(w + 6 * MB);                // [6,14)  bf16 LN1(Q)
  u16* Kb  = (u16*)(w + 14 * MB);               // [14,22) bf16 K
  u16* Vb  = (u16*)(w + 22 * MB);               // [22,30) bf16 V
  u16* qb  = (u16*)(w + 30 * MB);               // [30,38)
  u16* kb  = (u16*)(w + 38 * MB);               // [38,46)
  u16* vtb = (u16*)(w + 46 * MB);               // [46,54)
  u16* ctx = (u16*)(w + 54 * MB);               // [54,62)
  float* po = (float*)(w + 62 * MB);            // [62,94) 2 x 16 MB fp32 partial O
  float* pl = (float*)(w + 6 * MB);             // 512 KB in Qn region (dead after qkv)
  float* X = (float*)(w + 94 * MB);             // [94,110) fp32 X = Q + attn_out
  u16* Xn  = (u16*)(w + 6 * MB);                // reuse Qn region (after merge)
  u16* hb  = (u16*)(w + 14 * MB);               // [14,46) 32 MB (dead after attn)

  prep_weights<<<dim3(64, 6), 256, 0, stream>>>(W_q, W_k, W_v, W_o, w1, w2,
                                                wqkvT, woT, w1b, w2b);
  ln_cast<true><<<8192, 128, 0, stream>>>(Q, ln1_g, ln1_b, Qn, K, V, Kb, Vb);
  gemm_qkv<<<dim3(64, 12), 256, 0, stream>>>(Qn, Kb, Vb, wqkvT, qb, kb, vtb);
  attn_kernel<<<dim3(32, 16, 2), 256, 0, stream>>>(qb, kb, vtb, po, pl);
  attn_merge<<<8192, 128, 0, stream>>>(po, pl, ctx);
  gemm_bt<2, 128, 2><<<dim3(64, 4), 256, 0, stream>>>(ctx, woT, 8192, 512, 512, X, nullptr, Q);
  ln_cast<false><<<8192, 128, 0, stream>>>(X, ln2_g, ln2_b, Xn, nullptr, nullptr, nullptr, nullptr);
  gemm_bt<3, 128, 3><<<dim3(64, 16), 256, 0, stream>>>(Xn, w1b, 8192, 2048, 512, hb, b1, nullptr);
  gemm_bt<4, 128, 2><<<dim3(64, 4), 256, 0, stream>>>(hb, w2b, 8192, 512, 2048, (float*)d_out, b2, X);
}